// Round 1
// baseline (404.287 us; speedup 1.0000x reference)
//
#include <hip/hip_runtime.h>
#include <stdint.h>

// Problem constants: B=4, S=2048, D_IN=D_MODEL=1024.
// Pipeline:
//   1) absmax of each W (atomicMax on uint-encoded positive floats)
//   2) quantize W: rintf(w/s)*s, s=maxabs/128; emit W^T in bf16
//   3) cast q,k,v fp32 -> bf16
//   4) proj GEMMs (A[M,K] x Bt[N,K]) bf16 MFMA, +bias; v-proj stores vp^T
//   5) logits = qp x kp^T / 32 (batched), bf16 -> P
//   6) row softmax on P in place
//   7) out = P x vpT^T -> fp32 d_out
// Workspace needed ~102 MB (see layout in kernel_launch).

typedef unsigned short ushort_t;
typedef __attribute__((ext_vector_type(8))) short short8;
typedef __bf16 bf16x8 __attribute__((ext_vector_type(8)));
typedef __attribute__((ext_vector_type(4))) float floatx4;

__device__ __forceinline__ ushort_t f2bf(float x) {
  unsigned u = __float_as_uint(x);
  unsigned r = (u + 0x7fffu + ((u >> 16) & 1u)) >> 16;  // RNE
  return (ushort_t)r;
}
__device__ __forceinline__ float bf2f(ushort_t u) {
  return __uint_as_float(((unsigned)u) << 16);
}

__device__ __forceinline__ void gl_lds16(const ushort_t* g, ushort_t* l) {
  __builtin_amdgcn_global_load_lds(
      (const __attribute__((address_space(1))) unsigned int*)g,
      (__attribute__((address_space(3))) unsigned int*)l, 16, 0, 0);
}

#define BM 128
#define BN 128
#define BK 32

// CMODE: 0 = bf16 store C[gm*ldc+gn]; 1 = bf16 transposed store for vpT
//        (vpT[b][n][s], b=gm>>11, s=gm&2047); 2 = fp32 store C[gm*ldc+gn]
template <int CMODE>
__global__ __launch_bounds__(256, 2) void gemm_bt(
    const ushort_t* __restrict__ A, const ushort_t* __restrict__ Bt,
    void* __restrict__ Cv, const float* __restrict__ bias, int K, int ldc,
    float alpha, long strideA, long strideB, long strideC) {
  __shared__ __attribute__((aligned(16))) ushort_t sA[BM * BK];
  __shared__ __attribute__((aligned(16))) ushort_t sB[BN * BK];

  const int t = threadIdx.x;
  const int lane = t & 63;
  const int wave = t >> 6;
  const int bn = blockIdx.x, bm = blockIdx.y, bz = blockIdx.z;

  const ushort_t* Ab = A + (long)bz * strideA;
  const ushort_t* Bb = Bt + (long)bz * strideB;

  const long a_row0 = (long)bm * BM;
  const long b_row0 = (long)bn * BN;

  const int crow = t >> 2;      // staging row within tile half (0..63)
  const int ck = (t & 3) * 8;   // staging k-offset in elements

  const ushort_t* gA0 = Ab + (a_row0 + crow) * (long)K + ck;
  const ushort_t* gA1 = gA0 + 64L * K;
  const ushort_t* gB0 = Bb + (b_row0 + crow) * (long)K + ck;
  const ushort_t* gB1 = gB0 + 64L * K;

  // LDS dest: wave-uniform base + lane*16B (global_load_lds constraint)
  ushort_t* lA0 = sA + wave * 512;
  ushort_t* lA1 = sA + 2048 + wave * 512;
  ushort_t* lB0 = sB + wave * 512;
  ushort_t* lB1 = sB + 2048 + wave * 512;

  floatx4 acc[4][4];
#pragma unroll
  for (int i = 0; i < 4; ++i)
#pragma unroll
    for (int j = 0; j < 4; ++j) acc[i][j] = {0.f, 0.f, 0.f, 0.f};

  const int wm = (wave & 1) * 64;
  const int wn = (wave >> 1) * 64;
  const int fr = lane & 15;
  const int fk = (lane >> 4) * 8;

  for (int k0 = 0; k0 < K; k0 += BK) {
    gl_lds16(gA0, lA0);
    gl_lds16(gA1, lA1);
    gl_lds16(gB0, lB0);
    gl_lds16(gB1, lB1);
    gA0 += BK; gA1 += BK; gB0 += BK; gB1 += BK;
    __syncthreads();  // drains vmcnt: staging complete

    bf16x8 af[4], bfr[4];
#pragma unroll
    for (int i = 0; i < 4; ++i) {
      af[i] = *(const bf16x8*)&sA[(wm + i * 16 + fr) * BK + fk];
      bfr[i] = *(const bf16x8*)&sB[(wn + i * 16 + fr) * BK + fk];
    }
#pragma unroll
    for (int mi = 0; mi < 4; ++mi)
#pragma unroll
      for (int ni = 0; ni < 4; ++ni)
        acc[mi][ni] = __builtin_amdgcn_mfma_f32_16x16x32_bf16(
            af[mi], bfr[ni], acc[mi][ni], 0, 0, 0);
    __syncthreads();  // compute reads done before next stage overwrites
  }

  // C/D layout: row=(lane>>4)*4+reg, col=lane&15  [measured m89/m91]
  const int r0 = (lane >> 4) * 4;
  const int cc = lane & 15;
#pragma unroll
  for (int mi = 0; mi < 4; ++mi) {
#pragma unroll
    for (int ni = 0; ni < 4; ++ni) {
#pragma unroll
      for (int r = 0; r < 4; ++r) {
        long gm = a_row0 + wm + mi * 16 + r0 + r;
        long gn = b_row0 + wn + ni * 16 + cc;
        float v = acc[mi][ni][r] * alpha;
        if (bias) v += bias[gn];
        if (CMODE == 0) {
          ((ushort_t*)Cv)[(long)bz * strideC + gm * ldc + gn] = f2bf(v);
        } else if (CMODE == 1) {
          long b = gm >> 11, s = gm & 2047;
          ((ushort_t*)Cv)[b * (2048L * 1024L) + gn * 2048L + s] = f2bf(v);
        } else {
          ((float*)Cv)[(long)bz * strideC + gm * ldc + gn] = v;
        }
      }
    }
  }
}

__global__ __launch_bounds__(256) void absmax_k(
    const float* __restrict__ W0, const float* __restrict__ W1,
    const float* __restrict__ W2, unsigned* __restrict__ outv) {
  const float* W = blockIdx.z == 0 ? W0 : (blockIdx.z == 1 ? W1 : W2);
  float m = 0.f;
  const long n = 1024L * 1024L;
  for (long i = (long)blockIdx.x * blockDim.x + threadIdx.x; i < n;
       i += (long)gridDim.x * blockDim.x)
    m = fmaxf(m, fabsf(W[i]));
  for (int off = 32; off; off >>= 1) m = fmaxf(m, __shfl_xor(m, off));
  __shared__ float red[4];
  int lane = threadIdx.x & 63, wave = threadIdx.x >> 6;
  if (lane == 0) red[wave] = m;
  __syncthreads();
  if (threadIdx.x == 0) {
    m = fmaxf(fmaxf(red[0], red[1]), fmaxf(red[2], red[3]));
    atomicMax(&outv[blockIdx.z], __float_as_uint(m));  // positive floats: uint order
  }
}

__global__ __launch_bounds__(256) void quant_w_k(
    const float* __restrict__ W0, const float* __restrict__ W1,
    const float* __restrict__ W2, const unsigned* __restrict__ scales,
    ushort_t* __restrict__ Wt) {
  const int z = blockIdx.z;
  const float* W = z == 0 ? W0 : (z == 1 ? W1 : W2);
  const float s = __uint_as_float(scales[z]) * (1.0f / 128.0f);
  __shared__ float tile[32][33];
  const int tx = threadIdx.x & 31, ty = threadIdx.x >> 5;
  const int k0 = blockIdx.y * 32, n0 = blockIdx.x * 32;
#pragma unroll
  for (int i = 0; i < 4; ++i)
    tile[ty + i * 8][tx] = W[(long)(k0 + ty + i * 8) * 1024 + n0 + tx];
  __syncthreads();
  ushort_t* wt = Wt + (long)z * 1024 * 1024;
#pragma unroll
  for (int i = 0; i < 4; ++i) {
    float w = tile[tx][ty + i * 8];
    float qv = rintf(w / s) * s;  // rintf = round-half-even = jnp.round
    wt[(long)(n0 + ty + i * 8) * 1024 + k0 + tx] = f2bf(qv);
  }
}

__global__ __launch_bounds__(256) void cast3_k(
    const float* __restrict__ q, const float* __restrict__ k,
    const float* __restrict__ v, ushort_t* __restrict__ qb,
    ushort_t* __restrict__ kb, ushort_t* __restrict__ vb) {
  const int z = blockIdx.z;
  const float4* src = (const float4*)(z == 0 ? q : (z == 1 ? k : v));
  ushort_t* dst = z == 0 ? qb : (z == 1 ? kb : vb);
  const long nv = (4L * 2048 * 1024) / 4;
  for (long i = (long)blockIdx.x * blockDim.x + threadIdx.x; i < nv;
       i += (long)gridDim.x * blockDim.x) {
    float4 f = src[i];
    ushort4 u4;
    u4.x = f2bf(f.x); u4.y = f2bf(f.y); u4.z = f2bf(f.z); u4.w = f2bf(f.w);
    *(ushort4*)(dst + i * 4) = u4;
  }
}

__global__ __launch_bounds__(256) void softmax_k(ushort_t* __restrict__ P) {
  const long row = blockIdx.x;
  ushort_t* p = P + row * 2048;
  const int t = threadIdx.x;
  const int lane = t & 63, wave = t >> 6;
  short8 v8 = *(const short8*)&p[t * 8];
  float x[8];
#pragma unroll
  for (int j = 0; j < 8; ++j) x[j] = bf2f((ushort_t)v8[j]);
  float m = x[0];
#pragma unroll
  for (int j = 1; j < 8; ++j) m = fmaxf(m, x[j]);
  for (int off = 32; off; off >>= 1) m = fmaxf(m, __shfl_xor(m, off));
  __shared__ float rmax[4], rsum[4];
  if (lane == 0) rmax[wave] = m;
  __syncthreads();
  m = fmaxf(fmaxf(rmax[0], rmax[1]), fmaxf(rmax[2], rmax[3]));
  float s = 0.f;
#pragma unroll
  for (int j = 0; j < 8; ++j) {
    x[j] = __expf(x[j] - m);
    s += x[j];
  }
  for (int off = 32; off; off >>= 1) s += __shfl_xor(s, off);
  if (lane == 0) rsum[wave] = s;
  __syncthreads();
  s = rsum[0] + rsum[1] + rsum[2] + rsum[3];
  float inv = 1.0f / s;
  short8 o8;
#pragma unroll
  for (int j = 0; j < 8; ++j) o8[j] = (short)f2bf(x[j] * inv);
  *(short8*)&p[t * 8] = o8;
}

extern "C" void kernel_launch(void* const* d_in, const int* in_sizes, int n_in,
                              void* d_out, int out_size, void* d_ws,
                              size_t ws_size, hipStream_t stream) {
  const float* q = (const float*)d_in[0];
  const float* k = (const float*)d_in[1];
  const float* v = (const float*)d_in[2];
  const float* Wq = (const float*)d_in[3];
  const float* bq = (const float*)d_in[4];
  const float* Wk = (const float*)d_in[5];
  const float* bk = (const float*)d_in[6];
  const float* Wv = (const float*)d_in[7];
  const float* bv = (const float*)d_in[8];
  float* out = (float*)d_out;
  char* ws = (char*)d_ws;

  // Workspace layout (bytes). Total required: 106,955,008 (~102 MB).
  unsigned* scales = (unsigned*)ws;                    // 64 B
  ushort_t* Wt = (ushort_t*)(ws + 256);                // 3 * 2 MB (W^T bf16 quantized)
  ushort_t* qb = (ushort_t*)(ws + 6291712);            // 16 MB each
  ushort_t* kb = qb + 8388608;
  ushort_t* vb = kb + 8388608;
  ushort_t* qp = vb + 8388608;
  ushort_t* kp = qp + 8388608;
  ushort_t* vpT = kp + 8388608;                        // vp^T [4][1024][2048]
  ushort_t* P = qb;  // logits/probs [4][2048][2048] bf16, overlays dead qb+kb

  hipMemsetAsync(scales, 0, 64, stream);
  absmax_k<<<dim3(64, 1, 3), 256, 0, stream>>>(Wq, Wk, Wv, scales);
  quant_w_k<<<dim3(32, 32, 3), 256, 0, stream>>>(Wq, Wk, Wv, scales, Wt);
  cast3_k<<<dim3(512, 1, 3), 256, 0, stream>>>(q, k, v, qb, kb, vb);

  // Projections: M=8192, N=1024, K=1024
  gemm_bt<0><<<dim3(8, 64, 1), 256, 0, stream>>>(qb, Wt, qp, bq, 1024, 1024,
                                                 1.0f, 0, 0, 0);
  gemm_bt<0><<<dim3(8, 64, 1), 256, 0, stream>>>(kb, Wt + 1048576, kp, bk,
                                                 1024, 1024, 1.0f, 0, 0, 0);
  gemm_bt<1><<<dim3(8, 64, 1), 256, 0, stream>>>(vb, Wt + 2097152, vpT, bv,
                                                 1024, 0, 1.0f, 0, 0, 0);

  // logits = qp x kp^T / 32, batched over 4: M=N=2048, K=1024
  gemm_bt<0><<<dim3(16, 16, 4), 256, 0, stream>>>(
      qp, kp, P, nullptr, 1024, 2048, 0.03125f, 2097152L, 2097152L, 4194304L);

  softmax_k<<<8192, 256, 0, stream>>>(P);

  // out = P x vpT^T, batched: M=2048, N=1024, K=2048, fp32 store
  gemm_bt<2><<<dim3(8, 16, 4), 256, 0, stream>>>(
      P, vpT, out, nullptr, 2048, 1024, 1.0f, 4194304L, 2097152L, 2097152L);
}

// Round 2
// 353.897 us; speedup vs baseline: 1.1424x; 1.1424x over previous
//
#include <hip/hip_runtime.h>
#include <stdint.h>

// B=4, S=2048, D_IN=D_MODEL=1024.
// Pipeline: absmax(W) -> quantize W^T bf16 -> cast q,k,v bf16 ->
//   merged proj GEMM (z=3; v-proj stores vp^T) -> QK^T/32 -> softmax -> PV.
// GEMM: 128x128 tile, BK=64 (halved barrier count vs BK=32),
//   XOR chunk-swizzle (chunk ^= row&7) to kill ds_read_b128 bank conflicts
//   under the global_load_lds fixed-layout constraint.

typedef unsigned short ushort_t;
typedef __attribute__((ext_vector_type(8))) short short8;
typedef __bf16 bf16x8 __attribute__((ext_vector_type(8)));
typedef __attribute__((ext_vector_type(4))) float floatx4;

__device__ __forceinline__ ushort_t f2bf(float x) {
  unsigned u = __float_as_uint(x);
  unsigned r = (u + 0x7fffu + ((u >> 16) & 1u)) >> 16;  // RNE
  return (ushort_t)r;
}
__device__ __forceinline__ float bf2f(ushort_t u) {
  return __uint_as_float(((unsigned)u) << 16);
}

__device__ __forceinline__ void gl_lds16(const ushort_t* g, ushort_t* l) {
  __builtin_amdgcn_global_load_lds(
      (const __attribute__((address_space(1))) unsigned int*)g,
      (__attribute__((address_space(3))) unsigned int*)l, 16, 0, 0);
}

#define BM 128
#define BN 128
#define BK 64

// CMODE: 0 = bf16 store Cz[gm*ldc+gn]
//        1 = bf16 transposed store vpT[b][gn][s] (b=gm>>11, s=gm&2047), ushort4
//        2 = fp32 store Cz[gm*ldc+gn]
//        3 = merged proj: bz<2 -> mode 0 (bias0/bias1); bz==2 -> mode 1 (bias2)
template <int CMODE>
__global__ __launch_bounds__(256, 2) void gemm_bt(
    const ushort_t* __restrict__ A, const ushort_t* __restrict__ Bt,
    void* __restrict__ Cv, const float* __restrict__ bias0,
    const float* __restrict__ bias1, const float* __restrict__ bias2, int K,
    int ldc, float alpha, long strideA, long strideB, long strideC) {
  __shared__ __attribute__((aligned(16))) ushort_t sA[BM * BK];
  __shared__ __attribute__((aligned(16))) ushort_t sB[BN * BK];

  const int t = threadIdx.x;
  const int lane = t & 63;
  const int wave = t >> 6;
  const int bn = blockIdx.x, bm = blockIdx.y, bz = blockIdx.z;

  const ushort_t* Ab = A + (long)bz * strideA;
  const ushort_t* Bb = Bt + (long)bz * strideB;

  const long a_row0 = (long)bm * BM;
  const long b_row0 = (long)bn * BN;

  // Staging: 32 rows x 8 chunks(16B) per issue; 4 issues per matrix.
  // XOR swizzle: LDS[row][chunk] holds global[row][chunk ^ (row&7)].
  const int crow = t >> 3;                    // 0..31
  const int schunk = (t & 7) ^ (crow & 7);    // swizzled global chunk

  const ushort_t* gA = Ab + (a_row0 + crow) * (long)K + schunk * 8;
  const ushort_t* gB = Bb + (b_row0 + crow) * (long)K + schunk * 8;

  ushort_t* lA = sA + wave * 512;  // + issue*2048; HW adds lane*16B
  ushort_t* lB = sB + wave * 512;

  floatx4 acc[4][4];
#pragma unroll
  for (int i = 0; i < 4; ++i)
#pragma unroll
    for (int j = 0; j < 4; ++j) acc[i][j] = {0.f, 0.f, 0.f, 0.f};

  const int wm = (wave & 1) * 64;
  const int wn = (wave >> 1) * 64;
  const int fr = lane & 15;
  const int fg = lane >> 4;  // 0..3: which 16B chunk within a 32-k step

  // Fragment LDS byte offsets (constant over K-loop). row&7 == fr&7.
  int offA[2][4], offB[2][4];
#pragma unroll
  for (int s = 0; s < 2; ++s)
#pragma unroll
    for (int i = 0; i < 4; ++i) {
      int rowA = wm + i * 16 + fr;
      int rowB = wn + i * 16 + fr;
      int cg = s * 4 + fg;
      offA[s][i] = rowA * BK + ((cg ^ (rowA & 7)) * 8);
      offB[s][i] = rowB * BK + ((cg ^ (rowB & 7)) * 8);
    }

  for (int k0 = 0; k0 < K; k0 += BK) {
#pragma unroll
    for (int i = 0; i < 4; ++i) {
      gl_lds16(gA + (long)i * 32 * K, lA + i * 2048);
      gl_lds16(gB + (long)i * 32 * K, lB + i * 2048);
    }
    gA += BK;
    gB += BK;
    __syncthreads();  // staging complete

#pragma unroll
    for (int s = 0; s < 2; ++s) {
      bf16x8 af[4], bfr[4];
#pragma unroll
      for (int i = 0; i < 4; ++i) {
        af[i] = *(const bf16x8*)&sA[offA[s][i]];
        bfr[i] = *(const bf16x8*)&sB[offB[s][i]];
      }
#pragma unroll
      for (int mi = 0; mi < 4; ++mi)
#pragma unroll
        for (int ni = 0; ni < 4; ++ni)
          acc[mi][ni] = __builtin_amdgcn_mfma_f32_16x16x32_bf16(
              af[mi], bfr[ni], acc[mi][ni], 0, 0, 0);
    }
    __syncthreads();  // reads done before next stage overwrites
  }

  // C/D layout: row=(lane>>4)*4+reg, col=lane&15  [m89/m91]
  const int r0 = fg * 4;
  const int cc = fr;
  const float* bias = (CMODE == 3) ? (bz == 0 ? bias0 : (bz == 1 ? bias1 : bias2))
                                   : bias0;
  const bool tstore = (CMODE == 1) || (CMODE == 3 && bz == 2);
  ushort_t* Cz16 = (ushort_t*)Cv + (long)bz * strideC;
  float* Cz32 = (float*)Cv + (long)bz * strideC;

#pragma unroll
  for (int mi = 0; mi < 4; ++mi) {
#pragma unroll
    for (int ni = 0; ni < 4; ++ni) {
      long gm0 = a_row0 + wm + mi * 16 + r0;
      long gn = b_row0 + wn + ni * 16 + cc;
      float vv[4];
#pragma unroll
      for (int r = 0; r < 4; ++r) {
        vv[r] = acc[mi][ni][r] * alpha;
        if (bias) vv[r] += bias[gn];
      }
      if (CMODE == 2) {
#pragma unroll
        for (int r = 0; r < 4; ++r) Cz32[(gm0 + r) * ldc + gn] = vv[r];
      } else if (tstore) {
        // vp^T[b][gn][s]: r=0..3 contiguous in s; 8B-aligned packed store
        long b = gm0 >> 11, s = gm0 & 2047;
        ushort4 u4;
        u4.x = f2bf(vv[0]); u4.y = f2bf(vv[1]);
        u4.z = f2bf(vv[2]); u4.w = f2bf(vv[3]);
        *(ushort4*)&Cz16[b * (2048L * 1024L) + gn * 2048L + s] = u4;
      } else {
#pragma unroll
        for (int r = 0; r < 4; ++r) Cz16[(gm0 + r) * ldc + gn] = f2bf(vv[r]);
      }
    }
  }
}

__global__ __launch_bounds__(256) void absmax_k(
    const float* __restrict__ W0, const float* __restrict__ W1,
    const float* __restrict__ W2, unsigned* __restrict__ outv) {
  const float* W = blockIdx.z == 0 ? W0 : (blockIdx.z == 1 ? W1 : W2);
  float m = 0.f;
  const long n = 1024L * 1024L;
  for (long i = (long)blockIdx.x * blockDim.x + threadIdx.x; i < n;
       i += (long)gridDim.x * blockDim.x)
    m = fmaxf(m, fabsf(W[i]));
  for (int off = 32; off; off >>= 1) m = fmaxf(m, __shfl_xor(m, off));
  __shared__ float red[4];
  int lane = threadIdx.x & 63, wave = threadIdx.x >> 6;
  if (lane == 0) red[wave] = m;
  __syncthreads();
  if (threadIdx.x == 0) {
    m = fmaxf(fmaxf(red[0], red[1]), fmaxf(red[2], red[3]));
    atomicMax(&outv[blockIdx.z], __float_as_uint(m));  // positive floats: uint order
  }
}

__global__ __launch_bounds__(256) void quant_w_k(
    const float* __restrict__ W0, const float* __restrict__ W1,
    const float* __restrict__ W2, const unsigned* __restrict__ scales,
    ushort_t* __restrict__ Wt) {
  const int z = blockIdx.z;
  const float* W = z == 0 ? W0 : (z == 1 ? W1 : W2);
  const float s = __uint_as_float(scales[z]) * (1.0f / 128.0f);
  __shared__ float tile[32][33];
  const int tx = threadIdx.x & 31, ty = threadIdx.x >> 5;
  const int k0 = blockIdx.y * 32, n0 = blockIdx.x * 32;
#pragma unroll
  for (int i = 0; i < 4; ++i)
    tile[ty + i * 8][tx] = W[(long)(k0 + ty + i * 8) * 1024 + n0 + tx];
  __syncthreads();
  ushort_t* wt = Wt + (long)z * 1024 * 1024;
#pragma unroll
  for (int i = 0; i < 4; ++i) {
    float w = tile[tx][ty + i * 8];
    float qv = rintf(w / s) * s;  // rintf = round-half-even = jnp.round
    wt[(long)(n0 + ty + i * 8) * 1024 + k0 + tx] = f2bf(qv);
  }
}

__global__ __launch_bounds__(256) void cast3_k(
    const float* __restrict__ q, const float* __restrict__ k,
    const float* __restrict__ v, ushort_t* __restrict__ qb,
    ushort_t* __restrict__ kb, ushort_t* __restrict__ vb) {
  const int z = blockIdx.z;
  const float4* src = (const float4*)(z == 0 ? q : (z == 1 ? k : v));
  ushort_t* dst = z == 0 ? qb : (z == 1 ? kb : vb);
  const long nv = (4L * 2048 * 1024) / 4;
  for (long i = (long)blockIdx.x * blockDim.x + threadIdx.x; i < nv;
       i += (long)gridDim.x * blockDim.x) {
    float4 f = src[i];
    ushort4 u4;
    u4.x = f2bf(f.x); u4.y = f2bf(f.y); u4.z = f2bf(f.z); u4.w = f2bf(f.w);
    *(ushort4*)(dst + i * 4) = u4;
  }
}

__global__ __launch_bounds__(256) void softmax_k(ushort_t* __restrict__ P) {
  const long row = blockIdx.x;
  ushort_t* p = P + row * 2048;
  const int t = threadIdx.x;
  const int lane = t & 63, wave = t >> 6;
  short8 v8 = *(const short8*)&p[t * 8];
  float x[8];
#pragma unroll
  for (int j = 0; j < 8; ++j) x[j] = bf2f((ushort_t)v8[j]);
  float m = x[0];
#pragma unroll
  for (int j = 1; j < 8; ++j) m = fmaxf(m, x[j]);
  for (int off = 32; off; off >>= 1) m = fmaxf(m, __shfl_xor(m, off));
  __shared__ float rmax[4], rsum[4];
  if (lane == 0) rmax[wave] = m;
  __syncthreads();
  m = fmaxf(fmaxf(rmax[0], rmax[1]), fmaxf(rmax[2], rmax[3]));
  float s = 0.f;
#pragma unroll
  for (int j = 0; j < 8; ++j) {
    x[j] = __expf(x[j] - m);
    s += x[j];
  }
  for (int off = 32; off; off >>= 1) s += __shfl_xor(s, off);
  if (lane == 0) rsum[wave] = s;
  __syncthreads();
  s = rsum[0] + rsum[1] + rsum[2] + rsum[3];
  float inv = 1.0f / s;
  short8 o8;
#pragma unroll
  for (int j = 0; j < 8; ++j) o8[j] = (short)f2bf(x[j] * inv);
  *(short8*)&p[t * 8] = o8;
}

extern "C" void kernel_launch(void* const* d_in, const int* in_sizes, int n_in,
                              void* d_out, int out_size, void* d_ws,
                              size_t ws_size, hipStream_t stream) {
  const float* q = (const float*)d_in[0];
  const float* k = (const float*)d_in[1];
  const float* v = (const float*)d_in[2];
  const float* Wq = (const float*)d_in[3];
  const float* bq = (const float*)d_in[4];
  const float* Wk = (const float*)d_in[5];
  const float* bk = (const float*)d_in[6];
  const float* Wv = (const float*)d_in[7];
  const float* bv = (const float*)d_in[8];
  float* out = (float*)d_out;
  char* ws = (char*)d_ws;

  // Workspace layout (bytes). Total required: ~102 MB.
  unsigned* scales = (unsigned*)ws;          // 64 B
  ushort_t* Wt = (ushort_t*)(ws + 256);      // 3 * 2 MB (W^T bf16 quantized)
  ushort_t* qb = (ushort_t*)(ws + 6291712);  // 16 MB each: qb,kb,vb,qp,kp,vpT
  ushort_t* kb = qb + 8388608;
  ushort_t* vb = kb + 8388608;
  ushort_t* qp = vb + 8388608;
  ushort_t* kp = qp + 8388608;
  ushort_t* vpT = kp + 8388608;  // vp^T [4][1024][2048]
  ushort_t* P = qb;  // probs [4][2048][2048] bf16, overlays dead qb+kb

  hipMemsetAsync(scales, 0, 64, stream);
  absmax_k<<<dim3(64, 1, 3), 256, 0, stream>>>(Wq, Wk, Wv, scales);
  quant_w_k<<<dim3(32, 32, 3), 256, 0, stream>>>(Wq, Wk, Wv, scales, Wt);
  cast3_k<<<dim3(512, 1, 3), 256, 0, stream>>>(q, k, v, qb, kb, vb);

  // Merged projections: z=3, each M=8192, N=1024, K=1024.
  // C base = qp, strideC covers qp,kp; z==2 routes to vpT transposed store.
  gemm_bt<3><<<dim3(8, 64, 3), 256, 0, stream>>>(
      qb, Wt, qp, bq, bk, bv, 1024, 1024, 1.0f, 8388608L, 1048576L, 8388608L);

  // logits = qp x kp^T / 32, batched over 4: M=N=2048, K=1024
  gemm_bt<0><<<dim3(16, 16, 4), 256, 0, stream>>>(
      qp, kp, P, nullptr, nullptr, nullptr, 1024, 2048, 0.03125f, 2097152L,
      2097152L, 4194304L);

  softmax_k<<<8192, 256, 0, stream>>>(P);

  // out = P x vpT^T, batched: M=2048, N=1024, K=2048, fp32 store
  gemm_bt<2><<<dim3(8, 16, 4), 256, 0, stream>>>(
      P, vpT, out, nullptr, nullptr, nullptr, 2048, 1024, 1.0f, 4194304L,
      2097152L, 2097152L);
}

// Round 3
// 314.470 us; speedup vs baseline: 1.2856x; 1.1254x over previous
//
#include <hip/hip_runtime.h>
#include <stdint.h>

// B=4, S=2048, D_IN=D_MODEL=1024.
// Pipeline: absmax(W) -> quantize W^T bf16 -> cast q,k,v bf16 ->
//   merged proj GEMM (z=3; z<2 emits qp/kp as fp8-e4m3, z==2 stores vp^T bf16)
//   -> QK^T via MX-scaled fp8 MFMA (K=128, scale=1) -> softmax(bf16) -> PV bf16.
// Grids are bm-fastest so same-XCD blocks share A-stripes (L2 locality).
// fp8 is used ONLY where softmax averaging attenuates the noise (qp/kp);
// vp and P stay bf16 (their error enters the output unattenuated).

typedef unsigned short ushort_t;
typedef __attribute__((ext_vector_type(8))) short short8;
typedef __bf16 bf16x8 __attribute__((ext_vector_type(8)));
typedef __attribute__((ext_vector_type(4))) float floatx4;
typedef __attribute__((ext_vector_type(8))) int int8v;

__device__ __forceinline__ ushort_t f2bf(float x) {
  unsigned u = __float_as_uint(x);
  unsigned r = (u + 0x7fffu + ((u >> 16) & 1u)) >> 16;  // RNE
  return (ushort_t)r;
}
__device__ __forceinline__ float bf2f(ushort_t u) {
  return __uint_as_float(((unsigned)u) << 16);
}
__device__ __forceinline__ unsigned char f2fp8(float x) {
  // v_cvt_pk_fp8_f32 (RNE, saturating), take low byte
  return (unsigned char)(__builtin_amdgcn_cvt_pk_fp8_f32(x, x, 0, false) & 0xff);
}

__device__ __forceinline__ void gl_lds16(const void* g, void* l) {
  __builtin_amdgcn_global_load_lds(
      (const __attribute__((address_space(1))) unsigned int*)g,
      (__attribute__((address_space(3))) unsigned int*)l, 16, 0, 0);
}

#define BM 128
#define BN 128
#define BK 64

// CMODE: 2 = fp32 store Cz[gm*ldc+gn]
//        3 = merged proj: bz<2 -> fp8 store into Cv8 + bz*8388608 (bias0/1);
//                         bz==2 -> bf16 transposed vpT store into Cv (bias2)
// SWAP:  1 = bm from blockIdx.x (bm-fastest for XCD A-stripe sharing)
template <int CMODE, int SWAP>
__global__ __launch_bounds__(256, 2) void gemm_bt(
    const ushort_t* __restrict__ A, const ushort_t* __restrict__ Bt,
    void* __restrict__ Cv, void* __restrict__ Cv8,
    const float* __restrict__ bias0, const float* __restrict__ bias1,
    const float* __restrict__ bias2, int K, int ldc, float alpha, long strideA,
    long strideB, long strideC) {
  __shared__ __attribute__((aligned(16))) ushort_t sA[BM * BK];
  __shared__ __attribute__((aligned(16))) ushort_t sB[BN * BK];

  const int t = threadIdx.x;
  const int lane = t & 63;
  const int wave = t >> 6;
  const int bm = SWAP ? blockIdx.x : blockIdx.y;
  const int bn = SWAP ? blockIdx.y : blockIdx.x;
  const int bz = blockIdx.z;

  const ushort_t* Ab = A + (long)bz * strideA;
  const ushort_t* Bb = Bt + (long)bz * strideB;

  const long a_row0 = (long)bm * BM;
  const long b_row0 = (long)bn * BN;

  // Staging: 32 rows x 8 chunks(16B) per issue; 4 issues per matrix.
  // XOR swizzle: LDS[row][chunk] holds global[row][chunk ^ (row&7)].
  const int crow = t >> 3;                  // 0..31
  const int schunk = (t & 7) ^ (crow & 7);  // swizzled global chunk

  const ushort_t* gA = Ab + (a_row0 + crow) * (long)K + schunk * 8;
  const ushort_t* gB = Bb + (b_row0 + crow) * (long)K + schunk * 8;

  ushort_t* lA = sA + wave * 512;  // + issue*2048; HW adds lane*16B
  ushort_t* lB = sB + wave * 512;

  floatx4 acc[4][4];
#pragma unroll
  for (int i = 0; i < 4; ++i)
#pragma unroll
    for (int j = 0; j < 4; ++j) acc[i][j] = {0.f, 0.f, 0.f, 0.f};

  const int wm = (wave & 1) * 64;
  const int wn = (wave >> 1) * 64;
  const int fr = lane & 15;
  const int fg = lane >> 4;  // 0..3: which 16B chunk within a 32-k step

  int offA[2][4], offB[2][4];
#pragma unroll
  for (int s = 0; s < 2; ++s)
#pragma unroll
    for (int i = 0; i < 4; ++i) {
      int rowA = wm + i * 16 + fr;
      int rowB = wn + i * 16 + fr;
      int cg = s * 4 + fg;
      offA[s][i] = rowA * BK + ((cg ^ (rowA & 7)) * 8);
      offB[s][i] = rowB * BK + ((cg ^ (rowB & 7)) * 8);
    }

  for (int k0 = 0; k0 < K; k0 += BK) {
#pragma unroll
    for (int i = 0; i < 4; ++i) {
      gl_lds16(gA + (long)i * 32 * K, lA + i * 2048);
      gl_lds16(gB + (long)i * 32 * K, lB + i * 2048);
    }
    gA += BK;
    gB += BK;
    __syncthreads();  // staging complete

#pragma unroll
    for (int s = 0; s < 2; ++s) {
      bf16x8 af[4], bfr[4];
#pragma unroll
      for (int i = 0; i < 4; ++i) {
        af[i] = *(const bf16x8*)&sA[offA[s][i]];
        bfr[i] = *(const bf16x8*)&sB[offB[s][i]];
      }
#pragma unroll
      for (int mi = 0; mi < 4; ++mi)
#pragma unroll
        for (int ni = 0; ni < 4; ++ni)
          acc[mi][ni] = __builtin_amdgcn_mfma_f32_16x16x32_bf16(
              af[mi], bfr[ni], acc[mi][ni], 0, 0, 0);
    }
    __syncthreads();  // reads done before next stage overwrites
  }

  // C/D layout: row=(lane>>4)*4+reg, col=lane&15  [m89/m91]
  const int r0 = fg * 4;
  const int cc = fr;
  const float* bias =
      (CMODE == 3) ? (bz == 0 ? bias0 : (bz == 1 ? bias1 : bias2)) : bias0;
  float* Cz32 = (float*)Cv + (long)bz * strideC;
  unsigned char* C8 = (unsigned char*)Cv8 + (long)bz * 8388608L;
  ushort_t* CvpT = (ushort_t*)Cv;  // vpT base (CMODE 3, bz==2)

#pragma unroll
  for (int mi = 0; mi < 4; ++mi) {
#pragma unroll
    for (int ni = 0; ni < 4; ++ni) {
      long gm0 = a_row0 + wm + mi * 16 + r0;
      long gn = b_row0 + wn + ni * 16 + cc;
      float vv[4];
#pragma unroll
      for (int r = 0; r < 4; ++r) {
        vv[r] = acc[mi][ni][r] * alpha;
        if (bias) vv[r] += bias[gn];
      }
      if (CMODE == 2) {
#pragma unroll
        for (int r = 0; r < 4; ++r) Cz32[(gm0 + r) * ldc + gn] = vv[r];
      } else if (CMODE == 3 && bz == 2) {
        // vp^T[b][gn][s]: r=0..3 contiguous in s; 8B packed store
        long b = gm0 >> 11, s = gm0 & 2047;
        ushort4 u4;
        u4.x = f2bf(vv[0]); u4.y = f2bf(vv[1]);
        u4.z = f2bf(vv[2]); u4.w = f2bf(vv[3]);
        *(ushort4*)&CvpT[b * (2048L * 1024L) + gn * 2048L + s] = u4;
      } else {
        // fp8 e4m3 store: qp8/kp8 [8192][1024] row-major
#pragma unroll
        for (int r = 0; r < 4; ++r) C8[(gm0 + r) * 1024 + gn] = f2fp8(vv[r]);
      }
    }
  }
}

// QK^T with MX-scaled fp8 MFMA: K=128/instr, scale=2^0 (E8M0 127).
// A=qp8, B=kp8, both [4][2048][1024] fp8 e4m3; P bf16 [4][2048][2048], /32.
__global__ __launch_bounds__(256, 2) void qk_fp8(
    const unsigned char* __restrict__ Q8, const unsigned char* __restrict__ K8,
    ushort_t* __restrict__ P) {
  __shared__ __attribute__((aligned(16))) unsigned char sA[128 * 128];
  __shared__ __attribute__((aligned(16))) unsigned char sB[128 * 128];
  const int t = threadIdx.x;
  const int lane = t & 63, wave = t >> 6;
  const int bm = blockIdx.x, bn = blockIdx.y, bz = blockIdx.z;

  const unsigned char* Ab = Q8 + (long)bz * 2097152L + (long)bm * 128 * 1024;
  const unsigned char* Bb = K8 + (long)bz * 2097152L + (long)bn * 128 * 1024;

  // Staging: row = 128 B (BK=128 fp8). 256 thr x 16B = 32 rows/issue, 4 issues.
  const int crow = t >> 3;
  const int schunk = (t & 7) ^ (crow & 7);
  const unsigned char* gA = Ab + crow * 1024 + schunk * 16;
  const unsigned char* gB = Bb + crow * 1024 + schunk * 16;
  unsigned char* lA = sA + wave * 1024;  // + issue*4096; HW adds lane*16B
  unsigned char* lB = sB + wave * 1024;

  floatx4 acc[4][4];
#pragma unroll
  for (int i = 0; i < 4; ++i)
#pragma unroll
    for (int j = 0; j < 4; ++j) acc[i][j] = {0.f, 0.f, 0.f, 0.f};

  const int wm = (wave & 1) * 64;
  const int wn = (wave >> 1) * 64;
  const int fr = lane & 15;
  const int fg = lane >> 4;  // quad: k-bytes [fg*32, fg*32+32)

  int offA[4][2], offB[4][2];
#pragma unroll
  for (int i = 0; i < 4; ++i) {
    int rA = wm + i * 16 + fr;
    int rB = wn + i * 16 + fr;
    offA[i][0] = rA * 128 + (((2 * fg) ^ (rA & 7)) * 16);
    offA[i][1] = rA * 128 + (((2 * fg + 1) ^ (rA & 7)) * 16);
    offB[i][0] = rB * 128 + (((2 * fg) ^ (rB & 7)) * 16);
    offB[i][1] = rB * 128 + (((2 * fg + 1) ^ (rB & 7)) * 16);
  }

  for (int k0 = 0; k0 < 1024; k0 += 128) {
#pragma unroll
    for (int i = 0; i < 4; ++i) {
      gl_lds16(gA + (long)i * 32 * 1024, lA + i * 4096);
      gl_lds16(gB + (long)i * 32 * 1024, lB + i * 4096);
    }
    gA += 128;
    gB += 128;
    __syncthreads();

    int8v af[4], bfr[4];
#pragma unroll
    for (int i = 0; i < 4; ++i) {
      int4 lo = *(const int4*)&sA[offA[i][0]];
      int4 hi = *(const int4*)&sA[offA[i][1]];
      af[i][0] = lo.x; af[i][1] = lo.y; af[i][2] = lo.z; af[i][3] = lo.w;
      af[i][4] = hi.x; af[i][5] = hi.y; af[i][6] = hi.z; af[i][7] = hi.w;
      int4 lo2 = *(const int4*)&sB[offB[i][0]];
      int4 hi2 = *(const int4*)&sB[offB[i][1]];
      bfr[i][0] = lo2.x; bfr[i][1] = lo2.y; bfr[i][2] = lo2.z; bfr[i][3] = lo2.w;
      bfr[i][4] = hi2.x; bfr[i][5] = hi2.y; bfr[i][6] = hi2.z; bfr[i][7] = hi2.w;
    }
#pragma unroll
    for (int mi = 0; mi < 4; ++mi)
#pragma unroll
      for (int ni = 0; ni < 4; ++ni)
        acc[mi][ni] = __builtin_amdgcn_mfma_scale_f32_16x16x128_f8f6f4(
            af[mi], bfr[ni], acc[mi][ni], 0, 0, 0, 127, 0, 127);
    __syncthreads();
  }

  const int r0 = fg * 4;
  const int cc = fr;
#pragma unroll
  for (int mi = 0; mi < 4; ++mi)
#pragma unroll
    for (int ni = 0; ni < 4; ++ni)
#pragma unroll
      for (int r = 0; r < 4; ++r) {
        long gm = (long)bm * 128 + wm + mi * 16 + r0 + r;
        long gn = (long)bn * 128 + wn + ni * 16 + cc;
        P[(long)bz * 4194304L + gm * 2048 + gn] =
            f2bf(acc[mi][ni][r] * 0.03125f);
      }
}

__global__ __launch_bounds__(256) void absmax_k(
    const float* __restrict__ W0, const float* __restrict__ W1,
    const float* __restrict__ W2, unsigned* __restrict__ outv) {
  const float* W = blockIdx.z == 0 ? W0 : (blockIdx.z == 1 ? W1 : W2);
  float m = 0.f;
  const long n = 1024L * 1024L;
  for (long i = (long)blockIdx.x * blockDim.x + threadIdx.x; i < n;
       i += (long)gridDim.x * blockDim.x)
    m = fmaxf(m, fabsf(W[i]));
  for (int off = 32; off; off >>= 1) m = fmaxf(m, __shfl_xor(m, off));
  __shared__ float red[4];
  int lane = threadIdx.x & 63, wave = threadIdx.x >> 6;
  if (lane == 0) red[wave] = m;
  __syncthreads();
  if (threadIdx.x == 0) {
    m = fmaxf(fmaxf(red[0], red[1]), fmaxf(red[2], red[3]));
    atomicMax(&outv[blockIdx.z], __float_as_uint(m));  // positive: uint order
  }
}

__global__ __launch_bounds__(256) void quant_w_k(
    const float* __restrict__ W0, const float* __restrict__ W1,
    const float* __restrict__ W2, const unsigned* __restrict__ scales,
    ushort_t* __restrict__ Wt) {
  const int z = blockIdx.z;
  const float* W = z == 0 ? W0 : (z == 1 ? W1 : W2);
  const float s = __uint_as_float(scales[z]) * (1.0f / 128.0f);
  __shared__ float tile[32][33];
  const int tx = threadIdx.x & 31, ty = threadIdx.x >> 5;
  const int k0 = blockIdx.y * 32, n0 = blockIdx.x * 32;
#pragma unroll
  for (int i = 0; i < 4; ++i)
    tile[ty + i * 8][tx] = W[(long)(k0 + ty + i * 8) * 1024 + n0 + tx];
  __syncthreads();
  ushort_t* wt = Wt + (long)z * 1024 * 1024;
#pragma unroll
  for (int i = 0; i < 4; ++i) {
    float w = tile[tx][ty + i * 8];
    float qv = rintf(w / s) * s;  // rintf = RNE = jnp.round
    wt[(long)(n0 + ty + i * 8) * 1024 + k0 + tx] = f2bf(qv);
  }
}

__global__ __launch_bounds__(256) void cast3_k(
    const float* __restrict__ q, const float* __restrict__ k,
    const float* __restrict__ v, ushort_t* __restrict__ qb,
    ushort_t* __restrict__ kb, ushort_t* __restrict__ vb) {
  const int z = blockIdx.z;
  const float4* src = (const float4*)(z == 0 ? q : (z == 1 ? k : v));
  ushort_t* dst = z == 0 ? qb : (z == 1 ? kb : vb);
  const long nv = (4L * 2048 * 1024) / 4;
  for (long i = (long)blockIdx.x * blockDim.x + threadIdx.x; i < nv;
       i += (long)gridDim.x * blockDim.x) {
    float4 f = src[i];
    ushort4 u4;
    u4.x = f2bf(f.x); u4.y = f2bf(f.y); u4.z = f2bf(f.z); u4.w = f2bf(f.w);
    *(ushort4*)(dst + i * 4) = u4;
  }
}

__global__ __launch_bounds__(256) void softmax_k(ushort_t* __restrict__ P) {
  const long row = blockIdx.x;
  ushort_t* p = P + row * 2048;
  const int t = threadIdx.x;
  const int lane = t & 63, wave = t >> 6;
  short8 v8 = *(const short8*)&p[t * 8];
  float x[8];
#pragma unroll
  for (int j = 0; j < 8; ++j) x[j] = bf2f((ushort_t)v8[j]);
  float m = x[0];
#pragma unroll
  for (int j = 1; j < 8; ++j) m = fmaxf(m, x[j]);
  for (int off = 32; off; off >>= 1) m = fmaxf(m, __shfl_xor(m, off));
  __shared__ float rmax[4], rsum[4];
  if (lane == 0) rmax[wave] = m;
  __syncthreads();
  m = fmaxf(fmaxf(rmax[0], rmax[1]), fmaxf(rmax[2], rmax[3]));
  float s = 0.f;
#pragma unroll
  for (int j = 0; j < 8; ++j) {
    x[j] = __expf(x[j] - m);
    s += x[j];
  }
  for (int off = 32; off; off >>= 1) s += __shfl_xor(s, off);
  if (lane == 0) rsum[wave] = s;
  __syncthreads();
  s = rsum[0] + rsum[1] + rsum[2] + rsum[3];
  float inv = 1.0f / s;
  short8 o8;
#pragma unroll
  for (int j = 0; j < 8; ++j) o8[j] = (short)f2bf(x[j] * inv);
  *(short8*)&p[t * 8] = o8;
}

extern "C" void kernel_launch(void* const* d_in, const int* in_sizes, int n_in,
                              void* d_out, int out_size, void* d_ws,
                              size_t ws_size, hipStream_t stream) {
  const float* q = (const float*)d_in[0];
  const float* k = (const float*)d_in[1];
  const float* v = (const float*)d_in[2];
  const float* Wq = (const float*)d_in[3];
  const float* bq = (const float*)d_in[4];
  const float* Wk = (const float*)d_in[5];
  const float* bk = (const float*)d_in[6];
  const float* Wv = (const float*)d_in[7];
  const float* bv = (const float*)d_in[8];
  float* out = (float*)d_out;
  char* ws = (char*)d_ws;

  // Workspace layout (bytes). Total: 106,955,008 (same as round-1, known ok).
  // scales @0 (256B); Wt @256 (6MB);
  // qb/kb/vb @6,291,712 (3x16MB, dead after proj; P overlays this region)
  // P @6,291,712 (64MB bf16 -> ends 73,400,576)
  // vpT @73,400,576 (16MB bf16)
  // qp8 @90,177,792 (8MB fp8); kp8 @98,566,400 (8MB fp8)
  unsigned* scales = (unsigned*)ws;
  ushort_t* Wt = (ushort_t*)(ws + 256);
  ushort_t* qb = (ushort_t*)(ws + 6291712);
  ushort_t* kb = qb + 8388608;
  ushort_t* vb = kb + 8388608;
  ushort_t* P = qb;
  ushort_t* vpT = (ushort_t*)(ws + 73400576);
  unsigned char* qp8 = (unsigned char*)(ws + 90177792);
  unsigned char* kp8 = (unsigned char*)(ws + 98566400);

  hipMemsetAsync(scales, 0, 64, stream);
  absmax_k<<<dim3(64, 1, 3), 256, 0, stream>>>(Wq, Wk, Wv, scales);
  quant_w_k<<<dim3(32, 32, 3), 256, 0, stream>>>(Wq, Wk, Wv, scales, Wt);
  cast3_k<<<dim3(512, 1, 3), 256, 0, stream>>>(q, k, v, qb, kb, vb);

  // Merged projections (bm-fastest grid): each M=8192, N=1024, K=1024.
  // z<2 -> fp8 into qp8/kp8 (stride 8MB); z==2 -> bf16 vpT transposed.
  gemm_bt<3, 1><<<dim3(64, 8, 3), 256, 0, stream>>>(
      qb, Wt, vpT, qp8, bq, bk, bv, 1024, 1024, 1.0f, 8388608L, 1048576L, 0L);

  // logits = qp x kp^T / 32 via MX-fp8: M=N=2048, K=1024, batched over 4
  qk_fp8<<<dim3(16, 16, 4), 256, 0, stream>>>(qp8, kp8, P);

  softmax_k<<<8192, 256, 0, stream>>>(P);

  // out = P x vpT^T (bm-fastest): M=2048, N=1024, K=2048, fp32 store
  gemm_bt<2, 1><<<dim3(16, 8, 4), 256, 0, stream>>>(
      P, vpT, out, nullptr, nullptr, nullptr, nullptr, 2048, 1024, 1.0f,
      4194304L, 2097152L, 2097152L);
}